// Round 1
// baseline (980.496 us; speedup 1.0000x reference)
//
#include <hip/hip_runtime.h>

// WindowAttention fused kernel for MI355X (gfx950).
// 1 block = 1 window (49 tokens). bf16 MFMA (16x16x32), fp32 accum.
// ws layout: [0, 1572864)  qkv_w rearranged bf16 B-fragments
//            [1572864, 2097152) proj_w rearranged bf16 B-fragments
//            [2097152, 2359296) gathered positional bias [16][64][64] f32

typedef __bf16 bf16x8 __attribute__((ext_vector_type(8)));
typedef float f32x4 __attribute__((ext_vector_type(4)));

#define SCALE_Q 0.17677669529663687f

__device__ __forceinline__ unsigned short f2bf(float f) {
    unsigned int u = __float_as_uint(f);
    u += 0x7FFFu + ((u >> 16) & 1u);
    return (unsigned short)(u >> 16);
}

__device__ __forceinline__ uint4 pack8(const unsigned short o[8]) {
    uint4 p;
    p.x = (unsigned)o[0] | ((unsigned)o[1] << 16);
    p.y = (unsigned)o[2] | ((unsigned)o[3] << 16);
    p.z = (unsigned)o[4] | ((unsigned)o[5] << 16);
    p.w = (unsigned)o[6] | ((unsigned)o[7] << 16);
    return p;
}

// ---------------- prep: weight rearrange + bias gather ----------------
__global__ void prep_kernel(const float* __restrict__ qkv_w,
                            const float* __restrict__ proj_w,
                            const float* __restrict__ bias_table,
                            unsigned short* __restrict__ wqkv_f,
                            unsigned short* __restrict__ wproj_f,
                            float* __restrict__ bias_f) {
    int b = blockIdx.x, t = threadIdx.x;
    if (b < 384) {
        // (which,h,ks,dh,l): B-frag for qkv GEMM. lane l needs
        // B[k = ks*32+(l>>4)*8+j][n = dh*16+(l&15)] = qkv_w[h*96+d*3+which][k]
        int gid = b * 256 + t;
        int l = gid & 63; int r = gid >> 6;
        int dh = r & 1; r >>= 1;
        int ks = r & 15; r >>= 4;
        int h = r & 15; int which = r >> 4;
        int d = dh * 16 + (l & 15);
        int row = h * 96 + d * 3 + which;
        int c0 = ks * 32 + (l >> 4) * 8;
        const float* src = qkv_w + row * 512 + c0;
        unsigned short o[8];
#pragma unroll
        for (int j = 0; j < 8; ++j) o[j] = f2bf(src[j]);
        *(uint4*)(wqkv_f + (size_t)gid * 8) = pack8(o);
    } else if (b < 512) {
        // (ks,nt,l): B-frag for proj GEMM.
        int gid = (b - 384) * 256 + t;
        int l = gid & 63; int r = gid >> 6;
        int nt = r & 31; int ks = r >> 5;
        int oc = nt * 16 + (l & 15);
        int c0 = ks * 32 + (l >> 4) * 8;
        const float* src = proj_w + oc * 512 + c0;
        unsigned short o[8];
#pragma unroll
        for (int j = 0; j < 8; ++j) o[j] = f2bf(src[j]);
        *(uint4*)(wproj_f + (size_t)gid * 8) = pack8(o);
    } else {
        // (h,i,j): gathered relative-position bias, padded with 0.
        int gid = (b - 512) * 256 + t;
        int j = gid & 63; int i = (gid >> 6) & 63; int h = gid >> 12;
        float v = 0.f;
        if (i < 49 && j < 49) {
            int ri = i / 7, ci = i % 7, rj = j / 7, cj = j % 7;
            int idx = (ri - rj + 6) * 13 + (ci - cj + 6);
            v = bias_table[idx * 16 + h];
        }
        bias_f[gid] = v;
    }
}

// ---------------- main fused kernel ----------------
__global__ __launch_bounds__(256, 1)
void winattn_kernel(const float* __restrict__ x,
                    const float* __restrict__ qkv_b,
                    const float* __restrict__ proj_b,
                    const unsigned short* __restrict__ wqkv_f,
                    const unsigned short* __restrict__ wproj_f,
                    const float* __restrict__ bias_f,
                    float* __restrict__ out) {
    // LDS layout (bytes):
    //  Xs   [64][512] bf16  XOR((row&7)<<4)   @ 0       65536
    //  q    [2][64][32] bf16 XOR((row&3)<<4)  @ 65536    8192
    //  k    [2][64][32] bf16 XOR((row&3)<<4)  @ 73728    8192
    //  vT   [2][32][64] bf16 XOR((d&7)<<4)    @ 81920    8192
    //  attn [64][512] bf16  XOR((row&7)<<4)   @ 90112   65536
    //    rows 49..63 of attn (never written as attn) host:
    //      scores fp32 [64] rows, stride 208B  @ attn+50176
    //      P bf16 [64][64] XOR((row&7)<<4)     @ attn+50176 (overwrites scores)
    __shared__ __align__(16) char smem[155648];
    char* Xs = smem;
    char* qbuf = smem + 65536;
    char* kbuf = smem + 73728;
    char* vbuf = smem + 81920;
    char* attn = smem + 90112;
    char* sco  = attn + 49 * 1024;

    const int tid = threadIdx.x;
    const int l = tid & 63;
    const int W = tid >> 6;      // wave id 0..3
    const int lr = l & 15;       // row-in-tile (A/B frag) / col (C frag)
    const int lg = l >> 4;       // k-group
    const int win = blockIdx.x;

    // ---- Stage 0: x window -> bf16 LDS (pad rows 49..63 with 0) ----
    {
        const float* xw = x + (size_t)win * (49 * 512);
        for (int idx = tid; idx < 49 * 128; idx += 256) {
            int row = idx >> 7, c4 = idx & 127;
            float4 v4 = *(const float4*)(xw + row * 512 + c4 * 4);
            ushort4 u;
            u.x = f2bf(v4.x); u.y = f2bf(v4.y); u.z = f2bf(v4.z); u.w = f2bf(v4.w);
            *(ushort4*)(Xs + ((row * 1024 + c4 * 8) ^ ((row & 7) << 4))) = u;
        }
        for (int idx = tid; idx < 15 * 128; idx += 256) {
            int row = 49 + (idx >> 7), c4 = idx & 127;
            ushort4 z; z.x = 0; z.y = 0; z.z = 0; z.w = 0;
            *(ushort4*)(Xs + ((row * 1024 + c4 * 8) ^ ((row & 7) << 4))) = z;
        }
    }
    __syncthreads();

    const f32x4 zf = {0.f, 0.f, 0.f, 0.f};

    for (int H = 0; H < 8; ++H) {          // head pairs (2H, 2H+1)
        // ---- Phase A: q/k/v for both heads ----
        {
            f32x4 acc[3][4];
#pragma unroll
            for (int s = 0; s < 3; ++s)
#pragma unroll
                for (int mt = 0; mt < 4; ++mt) acc[s][mt] = zf;

            int boff[3];
#pragma unroll
            for (int s = 0; s < 3; ++s) {
                int id = W + s * 4;                 // 0..11
                int hh = id / 6, r6 = id % 6;
                int which = r6 >> 1, dh = r6 & 1;
                int h = 2 * H + hh;
                boff[s] = (which * 16 + h) * 16384 + dh * 512 + l * 8;
            }
            for (int ks = 0; ks < 16; ++ks) {
                bf16x8 af[4];
#pragma unroll
                for (int mt = 0; mt < 4; ++mt) {
                    int row = mt * 16 + lr;
                    af[mt] = *(const bf16x8*)(Xs +
                        ((row * 1024 + ks * 64 + lg * 16) ^ ((row & 7) << 4)));
                }
#pragma unroll
                for (int s = 0; s < 3; ++s) {
                    bf16x8 bfr = *(const bf16x8*)(wqkv_f + boff[s] + ks * 1024);
#pragma unroll
                    for (int mt = 0; mt < 4; ++mt)
                        acc[s][mt] = __builtin_amdgcn_mfma_f32_16x16x32_bf16(
                            af[mt], bfr, acc[s][mt], 0, 0, 0);
                }
            }
            // C-write into q/k/vT
#pragma unroll
            for (int s = 0; s < 3; ++s) {
                int id = W + s * 4;
                int hh = id / 6, r6 = id % 6;
                int which = r6 >> 1, dh = r6 & 1;
                int h = 2 * H + hh;
                int d = dh * 16 + lr;
                float bias = qkv_b[h * 96 + d * 3 + which];
#pragma unroll
                for (int mt = 0; mt < 4; ++mt) {
                    if (which == 2) {
                        int t0 = mt * 16 + lg * 4;   // 4 consecutive tokens
                        ushort4 u;
                        u.x = f2bf(acc[s][mt][0] + bias);
                        u.y = f2bf(acc[s][mt][1] + bias);
                        u.z = f2bf(acc[s][mt][2] + bias);
                        u.w = f2bf(acc[s][mt][3] + bias);
                        *(ushort4*)(vbuf + hh * 4096 +
                            ((d * 128 + t0 * 2) ^ ((d & 7) << 4))) = u;
                    } else {
                        char* base = (which == 0) ? qbuf : kbuf;
                        float sc = (which == 0) ? SCALE_Q : 1.f;
#pragma unroll
                        for (int r = 0; r < 4; ++r) {
                            int row = mt * 16 + lg * 4 + r;
                            float v = (acc[s][mt][r] + bias) * sc;
                            *(unsigned short*)(base + hh * 4096 +
                                ((row * 64 + d * 2) ^ ((row & 3) << 4))) = f2bf(v);
                        }
                    }
                }
            }
        }
        __syncthreads();

        for (int hh = 0; hh < 2; ++hh) {
            int h = 2 * H + hh;
            // ---- Phase B: scores = q @ k^T (wave = M-tile) ----
            {
                int arow = W * 16 + lr;
                bf16x8 qa = *(const bf16x8*)(qbuf + hh * 4096 +
                    ((arow * 64 + lg * 16) ^ ((arow & 3) << 4)));
                f32x4 sa[4];
#pragma unroll
                for (int nt = 0; nt < 4; ++nt) {
                    int brow = nt * 16 + lr;
                    bf16x8 kf = *(const bf16x8*)(kbuf + hh * 4096 +
                        ((brow * 64 + lg * 16) ^ ((brow & 3) << 4)));
                    sa[nt] = __builtin_amdgcn_mfma_f32_16x16x32_bf16(qa, kf, zf, 0, 0, 0);
                }
#pragma unroll
                for (int nt = 0; nt < 4; ++nt) {
                    int col = nt * 16 + lr;
                    if (col < 49) {
#pragma unroll
                        for (int r = 0; r < 4; ++r) {
                            int row = W * 16 + lg * 4 + r;
                            *(float*)(sco + row * 208 + col * 4) = sa[nt][r];
                        }
                    }
                }
            }
            __syncthreads();
            // ---- Phase C: softmax (4 lanes per row) ----
            {
                int row = tid >> 2, sub = tid & 3;
                float sv[16], bv[16];
                const char* rb = sco + row * 208 + sub * 64;
                *(float4*)(&sv[0])  = *(const float4*)(rb);
                *(float4*)(&sv[4])  = *(const float4*)(rb + 16);
                *(float4*)(&sv[8])  = *(const float4*)(rb + 32);
                *(float4*)(&sv[12]) = *(const float4*)(rb + 48);
                const float* bb = bias_f + (h * 64 + row) * 64 + sub * 16;
                *(float4*)(&bv[0])  = *(const float4*)(bb);
                *(float4*)(&bv[4])  = *(const float4*)(bb + 4);
                *(float4*)(&bv[8])  = *(const float4*)(bb + 8);
                *(float4*)(&bv[12]) = *(const float4*)(bb + 12);
                float m = -1e30f;
#pragma unroll
                for (int e = 0; e < 16; ++e) {
                    int col = sub * 16 + e;
                    if (col < 49) { sv[e] += bv[e]; m = fmaxf(m, sv[e]); }
                }
                m = fmaxf(m, __shfl_xor(m, 1));
                m = fmaxf(m, __shfl_xor(m, 2));
                float sum = 0.f, pv[16];
#pragma unroll
                for (int e = 0; e < 16; ++e) {
                    int col = sub * 16 + e;
                    float pe = 0.f;
                    if (col < 49) { pe = __expf(sv[e] - m); sum += pe; }
                    pv[e] = pe;
                }
                sum += __shfl_xor(sum, 1);
                sum += __shfl_xor(sum, 2);
                float inv = 1.0f / sum;
                __syncthreads();   // all score reads done before P overwrites
                unsigned short ub[16];
#pragma unroll
                for (int e = 0; e < 16; ++e) ub[e] = f2bf(pv[e] * inv);
                int base = row * 128 + sub * 32;
                *(uint4*)(sco + ((base) ^ ((row & 7) << 4))) = pack8(&ub[0]);
                *(uint4*)(sco + ((base + 16) ^ ((row & 7) << 4))) = pack8(&ub[8]);
            }
            __syncthreads();
            // ---- Phase D: out_h = P @ v (wave = M-tile) ----
            {
                f32x4 oa[2] = {zf, zf};
#pragma unroll
                for (int ks = 0; ks < 2; ++ks) {
                    int prow = W * 16 + lr;
                    bf16x8 pa = *(const bf16x8*)(sco +
                        ((prow * 128 + ks * 64 + lg * 16) ^ ((prow & 7) << 4)));
#pragma unroll
                    for (int nt = 0; nt < 2; ++nt) {
                        int d = nt * 16 + lr;
                        bf16x8 vf = *(const bf16x8*)(vbuf + hh * 4096 +
                            ((d * 128 + ks * 64 + lg * 16) ^ ((d & 7) << 4)));
                        oa[nt] = __builtin_amdgcn_mfma_f32_16x16x32_bf16(pa, vf, oa[nt], 0, 0, 0);
                    }
                }
#pragma unroll
                for (int nt = 0; nt < 2; ++nt) {
                    int col = h * 32 + nt * 16 + lr;
#pragma unroll
                    for (int r = 0; r < 4; ++r) {
                        int row = W * 16 + lg * 4 + r;
                        if (row < 49)
                            *(unsigned short*)(attn +
                                ((row * 1024 + col * 2) ^ ((row & 7) << 4))) = f2bf(oa[nt][r]);
                    }
                }
            }
            __syncthreads();
        }
    }

    // ---- Phase E: proj (attn [64][512] @ proj_w^T) ----
    float* ow = out + (size_t)win * (49 * 512);
#pragma unroll 1
    for (int p = 0; p < 2; ++p) {
        f32x4 acc[4][4];
#pragma unroll
        for (int q4 = 0; q4 < 4; ++q4)
#pragma unroll
            for (int mt = 0; mt < 4; ++mt) acc[q4][mt] = zf;
        for (int ks = 0; ks < 16; ++ks) {
            bf16x8 af[4];
#pragma unroll
            for (int mt = 0; mt < 4; ++mt) {
                int row = mt * 16 + lr;
                af[mt] = *(const bf16x8*)(attn +
                    ((row * 1024 + ks * 64 + lg * 16) ^ ((row & 7) << 4)));
            }
#pragma unroll
            for (int q4 = 0; q4 < 4; ++q4) {
                int nt = W * 8 + p * 4 + q4;
                bf16x8 bfr = *(const bf16x8*)(wproj_f + ks * 16384 + nt * 512 + l * 8);
#pragma unroll
                for (int mt = 0; mt < 4; ++mt)
                    acc[q4][mt] = __builtin_amdgcn_mfma_f32_16x16x32_bf16(
                        af[mt], bfr, acc[q4][mt], 0, 0, 0);
            }
        }
#pragma unroll
        for (int q4 = 0; q4 < 4; ++q4) {
            int col = (W * 8 + p * 4 + q4) * 16 + lr;
            float pb = proj_b[col];
#pragma unroll
            for (int mt = 0; mt < 4; ++mt) {
#pragma unroll
                for (int r = 0; r < 4; ++r) {
                    int row = mt * 16 + lg * 4 + r;
                    if (row < 49) ow[row * 512 + col] = acc[q4][mt][r] + pb;
                }
            }
        }
    }
}

extern "C" void kernel_launch(void* const* d_in, const int* in_sizes, int n_in,
                              void* d_out, int out_size, void* d_ws, size_t ws_size,
                              hipStream_t stream) {
    const float* x          = (const float*)d_in[0];
    const float* qkv_w      = (const float*)d_in[1];
    const float* qkv_b      = (const float*)d_in[2];
    const float* proj_w     = (const float*)d_in[3];
    const float* proj_b     = (const float*)d_in[4];
    const float* bias_table = (const float*)d_in[5];

    if (ws_size < 2359296u) return;  // need 2.25 MB scratch
    unsigned short* wqkv_f = (unsigned short*)d_ws;
    unsigned short* wproj_f = wqkv_f + 786432;      // 1.5 MB in
    float* bias_f = (float*)(wproj_f + 262144);     // 2.0 MB in

    hipLaunchKernelGGL(prep_kernel, dim3(768), dim3(256), 0, stream,
                       qkv_w, proj_w, bias_table, wqkv_f, wproj_f, bias_f);
    hipLaunchKernelGGL(winattn_kernel, dim3(2048), dim3(256), 0, stream,
                       x, qkv_b, proj_b, wqkv_f, wproj_f, bias_f, (float*)d_out);
}

// Round 2
// 733.145 us; speedup vs baseline: 1.3374x; 1.3374x over previous
//
#include <hip/hip_runtime.h>

// WindowAttention for MI355X (gfx950) — round 2: 3-kernel split.
//  prep2:    weight rearrange (bf16) + gathered bias with -1e30 pad masks
//  attn_qkv: per-window QKV (X in registers) + attention (swapped QK^T,
//            wave-private P), writes compact bf16 attnout to ws
//  proj_gemm: 128x128 m97-style GEMM with global_load_lds + swizzled LDS
// Fallback: round-1 fused kernel if ws_size too small.
//
// ws layout (new path):
//  [0,        1572864)   wqkv_f   bf16 B-frags (which,h,ks,dh,lane,8)
//  [1572864,  2097152)   wproj_f  bf16 [n][k] row-major
//  [2097152,  2359296)   bias_f   f32 [16][64][64], -1e30 pads
//  [2359296,  +102760448) attnout bf16 [100352][512] row-major

typedef __bf16 bf16x8 __attribute__((ext_vector_type(8)));
typedef float f32x4 __attribute__((ext_vector_type(4)));

#define SCALE_Q 0.17677669529663687f
#define WS_NEW 105119744ull

__device__ __forceinline__ unsigned short f2bf(float f) {
    unsigned int u = __float_as_uint(f);
    u += 0x7FFFu + ((u >> 16) & 1u);
    return (unsigned short)(u >> 16);
}

__device__ __forceinline__ uint4 pack8(const unsigned short o[8]) {
    uint4 p;
    p.x = (unsigned)o[0] | ((unsigned)o[1] << 16);
    p.y = (unsigned)o[2] | ((unsigned)o[3] << 16);
    p.z = (unsigned)o[4] | ((unsigned)o[5] << 16);
    p.w = (unsigned)o[6] | ((unsigned)o[7] << 16);
    return p;
}

union BU8 { bf16x8 v; unsigned short s[8]; };

#define GLOAD16(g, l) __builtin_amdgcn_global_load_lds( \
    (__attribute__((address_space(1))) void*)(void*)(g), \
    (__attribute__((address_space(3))) void*)(l), 16, 0, 0)

// ---------------- prep (new path) ----------------
__global__ void prep2_kernel(const float* __restrict__ qkv_w,
                             const float* __restrict__ proj_w,
                             const float* __restrict__ bias_table,
                             unsigned short* __restrict__ wqkv_f,
                             unsigned short* __restrict__ wproj_f,
                             float* __restrict__ bias_f) {
    int b = blockIdx.x, t = threadIdx.x;
    if (b < 384) {
        // B-frag for qkv GEMM: elem = (((which*16+h)*32 + ks*2 + dh)*64 + l)*8
        int gid = b * 256 + t;
        int l = gid & 63; int r = gid >> 6;
        int dh = r & 1; r >>= 1;
        int ks = r & 15; r >>= 4;
        int h = r & 15; int which = r >> 4;
        int d = dh * 16 + (l & 15);
        int row = h * 96 + d * 3 + which;
        int c0 = ks * 32 + (l >> 4) * 8;
        const float* src = qkv_w + row * 512 + c0;
        unsigned short o[8];
#pragma unroll
        for (int j = 0; j < 8; ++j) o[j] = f2bf(src[j]);
        *(uint4*)(wqkv_f + (size_t)gid * 8) = pack8(o);
    } else if (b < 512) {
        // proj_w [n][k] f32 -> bf16 row-major copy
        int gid = (b - 384) * 256 + t;       // 32768 threads * 8 elems
        const float* src = proj_w + (size_t)gid * 8;
        unsigned short o[8];
#pragma unroll
        for (int j = 0; j < 8; ++j) o[j] = f2bf(src[j]);
        *(uint4*)(wproj_f + (size_t)gid * 8) = pack8(o);
    } else {
        // gathered bias [h][q 64][kv 64], pads = -1e30
        int gid = (b - 512) * 256 + t;       // 65536
        int j = gid & 63; int i = (gid >> 6) & 63; int h = gid >> 12;
        float v = -1e30f;
        if (i < 49 && j < 49) {
            int ri = i / 7, ci = i % 7, rj = j / 7, cj = j % 7;
            int idx = (ri - rj + 6) * 13 + (ci - cj + 6);
            v = bias_table[idx * 16 + h];
        }
        bias_f[gid] = v;
    }
}

// ---------------- K_A: QKV + attention ----------------
__global__ __launch_bounds__(256, 2)
void attn_qkv_kernel(const float* __restrict__ x,
                     const float* __restrict__ qkv_b,
                     const unsigned short* __restrict__ wqkv_f,
                     const float* __restrict__ bias_f,
                     unsigned short* __restrict__ attnout) {
    // LDS: qk[4 heads][64 t][128B] (q bytes 0-63, k bytes 64-127)  @0     32KB
    //      vt[4 heads][32 d][128B]                                  @32768 16KB
    //      P [4 waves][64 q][128B]                                  @49152 32KB
    __shared__ __align__(16) char smem[81920];
    const int tid = threadIdx.x;
    const int l = tid & 63;
    const int W = tid >> 6;
    const int lr = l & 15;
    const int lg = l >> 4;
    const int win = blockIdx.x;

    // ---- X rows (16 per wave) as bf16 A-frags in registers ----
    bf16x8 xf[16];
    {
        int trow = 16 * W + lr; if (trow > 48) trow = 48;   // clamp pads
        const float* xr = x + ((size_t)win * 49 + trow) * 512;
#pragma unroll
        for (int ks = 0; ks < 16; ++ks) {
            float4 a = *(const float4*)(xr + ks * 32 + lg * 8);
            float4 b = *(const float4*)(xr + ks * 32 + lg * 8 + 4);
            BU8 u;
            u.s[0] = f2bf(a.x); u.s[1] = f2bf(a.y); u.s[2] = f2bf(a.z); u.s[3] = f2bf(a.w);
            u.s[4] = f2bf(b.x); u.s[5] = f2bf(b.y); u.s[6] = f2bf(b.z); u.s[7] = f2bf(b.w);
            xf[ks] = u.v;
        }
    }

    const f32x4 zf = {0.f, 0.f, 0.f, 0.f};
    unsigned short* ao = attnout + (size_t)win * (49 * 512);

    for (int hg = 0; hg < 4; ++hg) {
        // ---- QKV phase: wave computes its 16 rows for 4 heads ----
        for (int h2 = 0; h2 < 4; ++h2) {
            int h = hg * 4 + h2;
            char* qk = smem + h2 * 8192;
            char* vt = smem + 32768 + h2 * 4096;
#pragma unroll 1
            for (int which = 0; which < 3; ++which) {
                f32x4 a0 = zf, a1 = zf;
                const unsigned short* bp =
                    wqkv_f + (size_t)(which * 16 + h) * 16384 + l * 8;
#pragma unroll
                for (int ks = 0; ks < 16; ++ks) {
                    bf16x8 b0 = *(const bf16x8*)(bp + ks * 1024);
                    bf16x8 b1 = *(const bf16x8*)(bp + ks * 1024 + 512);
                    a0 = __builtin_amdgcn_mfma_f32_16x16x32_bf16(xf[ks], b0, a0, 0, 0, 0);
                    a1 = __builtin_amdgcn_mfma_f32_16x16x32_bf16(xf[ks], b1, a1, 0, 0, 0);
                }
                float bias0 = qkv_b[h * 96 + lr * 3 + which];
                float bias1 = qkv_b[h * 96 + (16 + lr) * 3 + which];
                if (which == 2) {
                    int d0 = lr, d1 = 16 + lr;
#pragma unroll
                    for (int r = 0; r < 4; ++r) {
                        int t = 16 * W + 4 * lg + r;
                        *(unsigned short*)(vt + d0 * 128 + ((t * 2) ^ ((d0 & 7) << 4))) =
                            f2bf(a0[r] + bias0);
                        *(unsigned short*)(vt + d1 * 128 + ((t * 2) ^ ((d1 & 7) << 4))) =
                            f2bf(a1[r] + bias1);
                    }
                } else {
                    float sc = (which == 0) ? SCALE_Q : 1.0f;
                    int cb = which * 64;
#pragma unroll
                    for (int r = 0; r < 4; ++r) {
                        int t = 16 * W + 4 * lg + r;
                        int sw = (t & 7) << 4;
                        *(unsigned short*)(qk + t * 128 + ((cb + lr * 2) ^ sw)) =
                            f2bf((a0[r] + bias0) * sc);
                        *(unsigned short*)(qk + t * 128 + ((cb + 32 + lr * 2) ^ sw)) =
                            f2bf((a1[r] + bias1) * sc);
                    }
                }
            }
        }
        __syncthreads();

        // ---- Attention: wave W owns head hg*4+W, fully wave-local ----
        {
            int h = hg * 4 + W;
            char* qk = smem + W * 8192;
            char* vt = smem + 32768 + W * 4096;
            char* P  = smem + 49152 + W * 8192;

            bf16x8 kf[4], qf[4];
#pragma unroll
            for (int i = 0; i < 4; ++i) {
                int row = i * 16 + lr;
                int sw = (row & 7) << 4;
                qf[i] = *(const bf16x8*)(qk + row * 128 + ((lg * 16) ^ sw));
                kf[i] = *(const bf16x8*)(qk + row * 128 + ((64 + lg * 16) ^ sw));
            }
            // S^T[kv][q]: s[mt(kv)][qt(q)]
            f32x4 s[4][4];
#pragma unroll
            for (int mt = 0; mt < 4; ++mt)
#pragma unroll
                for (int qt = 0; qt < 4; ++qt)
                    s[mt][qt] = __builtin_amdgcn_mfma_f32_16x16x32_bf16(
                        kf[mt], qf[qt], zf, 0, 0, 0);
            // bias add: bias[q][kv], kv pads = -1e30
#pragma unroll
            for (int qt = 0; qt < 4; ++qt) {
                int q = qt * 16 + lr;
                const float* bb = bias_f + ((size_t)h * 64 + q) * 64;
#pragma unroll
                for (int mt = 0; mt < 4; ++mt) {
                    float4 b4 = *(const float4*)(bb + mt * 16 + lg * 4);
                    s[mt][qt][0] += b4.x; s[mt][qt][1] += b4.y;
                    s[mt][qt][2] += b4.z; s[mt][qt][3] += b4.w;
                }
            }
            // softmax per q (= column of S^T), then P -> LDS (bf16)
#pragma unroll
            for (int qt = 0; qt < 4; ++qt) {
                float m = -1e30f;
#pragma unroll
                for (int mt = 0; mt < 4; ++mt)
#pragma unroll
                    for (int r = 0; r < 4; ++r) m = fmaxf(m, s[mt][qt][r]);
                m = fmaxf(m, __shfl_xor(m, 16));
                m = fmaxf(m, __shfl_xor(m, 32));
                float sum = 0.f;
#pragma unroll
                for (int mt = 0; mt < 4; ++mt)
#pragma unroll
                    for (int r = 0; r < 4; ++r) {
                        float p = __expf(s[mt][qt][r] - m);
                        s[mt][qt][r] = p; sum += p;
                    }
                sum += __shfl_xor(sum, 16);
                sum += __shfl_xor(sum, 32);
                float inv = 1.0f / sum;
                int qrow = qt * 16 + lr;
                int sw = (qrow & 7) << 4;
#pragma unroll
                for (int mt = 0; mt < 4; ++mt) {
                    uint2 uv;
                    uv.x = (unsigned)f2bf(s[mt][qt][0] * inv) |
                           ((unsigned)f2bf(s[mt][qt][1] * inv) << 16);
                    uv.y = (unsigned)f2bf(s[mt][qt][2] * inv) |
                           ((unsigned)f2bf(s[mt][qt][3] * inv) << 16);
                    *(uint2*)(P + qrow * 128 + ((mt * 32 + lg * 8) ^ sw)) = uv;
                }
            }
            // PV: out[q][d] = P @ v   (v via vt[d][kv])
            bf16x8 vf[2][2];
#pragma unroll
            for (int ks = 0; ks < 2; ++ks)
#pragma unroll
                for (int nt = 0; nt < 2; ++nt) {
                    int d = nt * 16 + lr;
                    vf[ks][nt] = *(const bf16x8*)(vt + d * 128 +
                        ((ks * 64 + lg * 16) ^ ((d & 7) << 4)));
                }
            f32x4 o[4][2];
#pragma unroll
            for (int mt = 0; mt < 4; ++mt) {
                o[mt][0] = zf; o[mt][1] = zf;
                int q = mt * 16 + lr;
                int sw = (q & 7) << 4;
#pragma unroll
                for (int ks = 0; ks < 2; ++ks) {
                    bf16x8 pf = *(const bf16x8*)(P + q * 128 + ((ks * 64 + lg * 16) ^ sw));
                    o[mt][0] = __builtin_amdgcn_mfma_f32_16x16x32_bf16(pf, vf[ks][0], o[mt][0], 0, 0, 0);
                    o[mt][1] = __builtin_amdgcn_mfma_f32_16x16x32_bf16(pf, vf[ks][1], o[mt][1], 0, 0, 0);
                }
            }
#pragma unroll
            for (int mt = 0; mt < 4; ++mt)
#pragma unroll
                for (int nt = 0; nt < 2; ++nt)
#pragma unroll
                    for (int r = 0; r < 4; ++r) {
                        int q = mt * 16 + 4 * lg + r;
                        if (q < 49)
                            ao[q * 512 + h * 32 + nt * 16 + lr] = f2bf(o[mt][nt][r]);
                    }
        }
        __syncthreads();
    }
}

// ---------------- K_B: proj GEMM (m97-style 128x128) ----------------
__global__ __launch_bounds__(256, 2)
void proj_kernel(const unsigned short* __restrict__ attnout,
                 const unsigned short* __restrict__ wproj_f,
                 const float* __restrict__ proj_b,
                 float* __restrict__ out) {
    __shared__ __align__(16) char smem[32768];   // A 16KB | B 16KB
    char* As = smem;
    char* Bs = smem + 16384;

    int bid = blockIdx.x;
    int c = bid >> 2;
    int cs = (c & 7) * 98 + (c >> 3);            // XCD swizzle (784 = 8*98)
    int m0 = cs * 128;
    int n0 = (bid & 3) * 128;

    const int tid = threadIdx.x;
    const int l = tid & 63;
    const int W = tid >> 6;
    const int lr = l & 15;
    const int lg = l >> 4;
    const int Wm = W >> 1, Wn = W & 1;

    f32x4 acc[4][4];
    const f32x4 zf = {0.f, 0.f, 0.f, 0.f};
#pragma unroll
    for (int mt = 0; mt < 4; ++mt)
#pragma unroll
        for (int nt = 0; nt < 4; ++nt) acc[mt][nt] = zf;

    int rsub = l >> 3;                 // 0..7  (row within 8-row stage slice)
    int csub = l & 7;                  // 16B chunk
    int cswz = (csub ^ rsub) * 16;     // inverse-swizzled source chunk

#pragma unroll 1
    for (int kt = 0; kt < 8; ++kt) {
        // stage A,B tiles [128][64] bf16, pre-inverse-swizzled source
#pragma unroll
        for (int i = 0; i < 4; ++i) {
            int r = i * 32 + W * 8 + rsub;
            const char* srcA = (const char*)attnout +
                ((size_t)(m0 + r) * 512 + kt * 64) * 2 + cswz;
            GLOAD16(srcA, As + i * 4096 + W * 1024);
            const char* srcB = (const char*)wproj_f +
                ((size_t)(n0 + r) * 512 + kt * 64) * 2 + cswz;
            GLOAD16(srcB, Bs + i * 4096 + W * 1024);
        }
        __syncthreads();
#pragma unroll
        for (int ks = 0; ks < 2; ++ks) {
            bf16x8 af[4], bf[4];
#pragma unroll
            for (int mt = 0; mt < 4; ++mt) {
                int row = Wm * 64 + mt * 16 + lr;
                af[mt] = *(const bf16x8*)(As + row * 128 +
                    ((ks * 64 + lg * 16) ^ ((row & 7) << 4)));
            }
#pragma unroll
            for (int nt = 0; nt < 4; ++nt) {
                int row = Wn * 64 + nt * 16 + lr;
                bf[nt] = *(const bf16x8*)(Bs + row * 128 +
                    ((ks * 64 + lg * 16) ^ ((row & 7) << 4)));
            }
#pragma unroll
            for (int mt = 0; mt < 4; ++mt)
#pragma unroll
                for (int nt = 0; nt < 4; ++nt)
                    acc[mt][nt] = __builtin_amdgcn_mfma_f32_16x16x32_bf16(
                        af[mt], bf[nt], acc[mt][nt], 0, 0, 0);
        }
        __syncthreads();
    }
    // epilogue: out row == GEMM row (compact attnout)
#pragma unroll
    for (int nt = 0; nt < 4; ++nt) {
        int n = n0 + Wn * 64 + nt * 16 + lr;
        float pb = proj_b[n];
#pragma unroll
        for (int mt = 0; mt < 4; ++mt) {
#pragma unroll
            for (int r = 0; r < 4; ++r) {
                int m = m0 + Wm * 64 + mt * 16 + 4 * lg + r;
                out[(size_t)m * 512 + n] = acc[mt][nt][r] + pb;
            }
        }
    }
}

// =================== FALLBACK (round-1, proven) ===================
__global__ void prep_fb(const float* __restrict__ qkv_w,
                        const float* __restrict__ proj_w,
                        const float* __restrict__ bias_table,
                        unsigned short* __restrict__ wqkv_f,
                        unsigned short* __restrict__ wproj_f,
                        float* __restrict__ bias_f) {
    int b = blockIdx.x, t = threadIdx.x;
    if (b < 384) {
        int gid = b * 256 + t;
        int l = gid & 63; int r = gid >> 6;
        int dh = r & 1; r >>= 1;
        int ks = r & 15; r >>= 4;
        int h = r & 15; int which = r >> 4;
        int d = dh * 16 + (l & 15);
        int row = h * 96 + d * 3 + which;
        int c0 = ks * 32 + (l >> 4) * 8;
        const float* src = qkv_w + row * 512 + c0;
        unsigned short o[8];
#pragma unroll
        for (int j = 0; j < 8; ++j) o[j] = f2bf(src[j]);
        *(uint4*)(wqkv_f + (size_t)gid * 8) = pack8(o);
    } else if (b < 512) {
        int gid = (b - 384) * 256 + t;
        int l = gid & 63; int r = gid >> 6;
        int nt = r & 31; int ks = r >> 5;
        int oc = nt * 16 + (l & 15);
        int c0 = ks * 32 + (l >> 4) * 8;
        const float* src = proj_w + oc * 512 + c0;
        unsigned short o[8];
#pragma unroll
        for (int j = 0; j < 8; ++j) o[j] = f2bf(src[j]);
        *(uint4*)(wproj_f + (size_t)gid * 8) = pack8(o);
    } else {
        int gid = (b - 512) * 256 + t;
        int j = gid & 63; int i = (gid >> 6) & 63; int h = gid >> 12;
        float v = 0.f;
        if (i < 49 && j < 49) {
            int ri = i / 7, ci = i % 7, rj = j / 7, cj = j % 7;
            int idx = (ri - rj + 6) * 13 + (ci - cj + 6);
            v = bias_table[idx * 16 + h];
        }
        bias_f[gid] = v;
    }
}

__global__ __launch_bounds__(256, 1)
void winattn_fb(const float* __restrict__ x,
                const float* __restrict__ qkv_b,
                const float* __restrict__ proj_b,
                const unsigned short* __restrict__ wqkv_f,
                const unsigned short* __restrict__ wproj_f,
                const float* __restrict__ bias_f,
                float* __restrict__ out) {
    __shared__ __align__(16) char smem[155648];
    char* Xs = smem;
    char* qbuf = smem + 65536;
    char* kbuf = smem + 73728;
    char* vbuf = smem + 81920;
    char* attn = smem + 90112;
    char* sco  = attn + 49 * 1024;

    const int tid = threadIdx.x;
    const int l = tid & 63;
    const int W = tid >> 6;
    const int lr = l & 15;
    const int lg = l >> 4;
    const int win = blockIdx.x;

    {
        const float* xw = x + (size_t)win * (49 * 512);
        for (int idx = tid; idx < 49 * 128; idx += 256) {
            int row = idx >> 7, c4 = idx & 127;
            float4 v4 = *(const float4*)(xw + row * 512 + c4 * 4);
            ushort4 u;
            u.x = f2bf(v4.x); u.y = f2bf(v4.y); u.z = f2bf(v4.z); u.w = f2bf(v4.w);
            *(ushort4*)(Xs + ((row * 1024 + c4 * 8) ^ ((row & 7) << 4))) = u;
        }
        for (int idx = tid; idx < 15 * 128; idx += 256) {
            int row = 49 + (idx >> 7), c4 = idx & 127;
            ushort4 z; z.x = 0; z.y = 0; z.z = 0; z.w = 0;
            *(ushort4*)(Xs + ((row * 1024 + c4 * 8) ^ ((row & 7) << 4))) = z;
        }
    }
    __syncthreads();

    const f32x4 zf = {0.f, 0.f, 0.f, 0.f};

    for (int H = 0; H < 8; ++H) {
        {
            f32x4 acc[3][4];
#pragma unroll
            for (int s = 0; s < 3; ++s)
#pragma unroll
                for (int mt = 0; mt < 4; ++mt) acc[s][mt] = zf;
            int boff[3];
#pragma unroll
            for (int s = 0; s < 3; ++s) {
                int id = W + s * 4;
                int hh = id / 6, r6 = id % 6;
                int which = r6 >> 1, dh = r6 & 1;
                int h = 2 * H + hh;
                boff[s] = (which * 16 + h) * 16384 + dh * 512 + l * 8;
            }
            for (int ks = 0; ks < 16; ++ks) {
                bf16x8 af[4];
#pragma unroll
                for (int mt = 0; mt < 4; ++mt) {
                    int row = mt * 16 + lr;
                    af[mt] = *(const bf16x8*)(Xs +
                        ((row * 1024 + ks * 64 + lg * 16) ^ ((row & 7) << 4)));
                }
#pragma unroll
                for (int s = 0; s < 3; ++s) {
                    bf16x8 bfr = *(const bf16x8*)(wqkv_f + boff[s] + ks * 1024);
#pragma unroll
                    for (int mt = 0; mt < 4; ++mt)
                        acc[s][mt] = __builtin_amdgcn_mfma_f32_16x16x32_bf16(
                            af[mt], bfr, acc[s][mt], 0, 0, 0);
                }
            }
#pragma unroll
            for (int s = 0; s < 3; ++s) {
                int id = W + s * 4;
                int hh = id / 6, r6 = id % 6;
                int which = r6 >> 1, dh = r6 & 1;
                int h = 2 * H + hh;
                int d = dh * 16 + lr;
                float bias = qkv_b[h * 96 + d * 3 + which];
#pragma unroll
                for (int mt = 0; mt < 4; ++mt) {
                    if (which == 2) {
                        int t0 = mt * 16 + lg * 4;
                        ushort4 u;
                        u.x = f2bf(acc[s][mt][0] + bias);
                        u.y = f2bf(acc[s][mt][1] + bias);
                        u.z = f2bf(acc[s][mt][2] + bias);
                        u.w = f2bf(acc[s][mt][3] + bias);
                        *(ushort4*)(vbuf + hh * 4096 +
                            ((d * 128 + t0 * 2) ^ ((d & 7) << 4))) = u;
                    } else {
                        char* base = (which == 0) ? qbuf : kbuf;
                        float sc = (which == 0) ? SCALE_Q : 1.f;
#pragma unroll
                        for (int r = 0; r < 4; ++r) {
                            int row = mt * 16 + lg * 4 + r;
                            float v = (acc[s][mt][r] + bias) * sc;
                            *(unsigned short*)(base + hh * 4096 +
                                ((row * 64 + d * 2) ^ ((row & 3) << 4))) = f2bf(v);
                        }
                    }
                }
            }
        }
        __syncthreads();

        for (int hh = 0; hh < 2; ++hh) {
            int h = 2 * H + hh;
            {
                int arow = W * 16 + lr;
                bf16x8 qa = *(const bf16x8*)(qbuf + hh * 4096 +
                    ((arow * 64 + lg * 16) ^ ((arow & 3) << 4)));
                f32x4 sa[4];
#pragma unroll
                for (int nt = 0; nt < 4; ++nt) {
                    int brow = nt * 16 + lr;
                    bf16x8 kfr = *(const bf16x8*)(kbuf + hh * 4096 +
                        ((brow * 64 + lg * 16) ^ ((brow & 3) << 4)));
                    sa[nt] = __builtin_amdgcn_mfma_f32_16x16x32_bf16(qa, kfr, zf, 0, 0, 0);
                }
#pragma unroll
                for (int nt = 0; nt < 4; ++nt) {
                    int col = nt * 16 + lr;
                    if (col < 49) {
#pragma unroll
                        for (int r = 0; r < 4; ++r) {
                            int row = W * 16 + lg * 4 + r;
                            *(float*)(sco + row * 208 + col * 4) = sa[nt][r];
                        }
                    }
                }
            }
            __syncthreads();
            {
                int row = tid >> 2, sub = tid & 3;
                float sv[16], bv[16];
                const char* rb = sco + row * 208 + sub * 64;
                *(float4*)(&sv[0])  = *(const float4*)(rb);
                *(float4*)(&sv[4])  = *(const float4*)(rb + 16);
                *(float4*)(&sv[8])  = *(const float4*)(rb + 32);
                *(float4*)(&sv[12]) = *(const float4*)(rb + 48);
                const float* bb = bias_f + (h * 64 + row) * 64 + sub * 16;
                *(float4*)(&bv[0])  = *(const float4*)(bb);
                *(float4*)(&bv[4])  = *(const float4*)(bb + 4);
                *(float4*)(&bv[8])  = *(const float4*)(bb + 8);
                *(float4*)(&bv[12]) = *(const float4*)(bb + 12);
                float m = -1e30f;
#pragma unroll
                for (int e = 0; e < 16; ++e) {
                    int col = sub * 16 + e;
                    if (col < 49) { sv[e] += bv[e]; m = fmaxf(m, sv[e]); }
                }
                m = fmaxf(m, __shfl_xor(m, 1));
                m = fmaxf(m, __shfl_xor(m, 2));
                float sum = 0.f, pv[16];
#pragma unroll
                for (int e = 0; e < 16; ++e) {
                    int col = sub * 16 + e;
                    float pe = 0.f;
                    if (col < 49) { pe = __expf(sv[e] - m); sum += pe; }
                    pv[e] = pe;
                }
                sum += __shfl_xor(sum, 1);
                sum += __shfl_xor(sum, 2);
                float inv = 1.0f / sum;
                __syncthreads();
                unsigned short ub[16];
#pragma unroll
                for (int e = 0; e < 16; ++e) ub[e] = f2bf(pv[e] * inv);
                int base = row * 128 + sub * 32;
                *(uint4*)(sco + ((base) ^ ((row & 7) << 4))) = pack8(&ub[0]);
                *(uint4*)(sco + ((base + 16) ^ ((row & 7) << 4))) = pack8(&ub[8]);
            }
            __syncthreads();
            {
                f32x4 oa[2] = {zf, zf};
#pragma unroll
                for (int ks = 0; ks < 2; ++ks) {
                    int prow = W * 16 + lr;
                    bf16x8 pa = *(const bf16x8*)(sco +
                        ((prow * 128 + ks * 64 + lg * 16) ^ ((prow & 7) << 4)));
#pragma unroll
                    for (int nt = 0; nt < 2; ++nt) {
                        int d = nt * 16 + lr;
                        bf16x8 vfr = *(const bf16x8*)(vbuf + hh * 4096 +
                            ((d * 128 + ks * 64 + lg * 16) ^ ((d & 7) << 4)));
                        oa[nt] = __builtin_amdgcn_mfma_f32_16x16x32_bf16(pa, vfr, oa[nt], 0, 0, 0);
                    }
                }
#pragma unroll
                for (int nt = 0; nt < 2; ++nt) {
                    int col = h * 32 + nt * 16 + lr;
#pragma unroll
                    for (int r = 0; r < 4; ++r) {
                        int row = W * 16 + lg * 4 + r;
                        if (row < 49)
                            *(unsigned short*)(attn +
                                ((row * 1024 + col * 2) ^ ((row & 7) << 4))) = f2bf(oa[nt][r]);
                    }
                }
            }
            __syncthreads();
        }
    }

    float* ow = out + (size_t)win * (49 * 512);
#pragma unroll 1
    for (int p = 0; p < 2; ++p) {
        f32x4 acc[4][4];
#pragma unroll
        for (int q4 = 0; q4 < 4; ++q4)
#pragma unroll
            for (int mt = 0; mt < 4; ++mt) acc[q4][mt] = zf;
        for (int ks = 0; ks < 16; ++ks) {
            bf16x8 af[4];
#pragma unroll
            for (int mt = 0; mt < 4; ++mt) {
                int row = mt * 16 + lr;
                af[mt] = *(const bf16x8*)(attn +
                    ((row * 1024 + ks * 64 + lg * 16) ^ ((row & 7) << 4)));
            }
#pragma unroll
            for (int q4 = 0; q4 < 4; ++q4) {
                int nt = W * 8 + p * 4 + q4;
                bf16x8 bfr = *(const bf16x8*)(wproj_f + ks * 16384 + nt * 512 + l * 8);
#pragma unroll
                for (int mt = 0; mt < 4; ++mt)
                    acc[q4][mt] = __builtin_amdgcn_mfma_f32_16x16x32_bf16(
                        af[mt], bfr, acc[q4][mt], 0, 0, 0);
            }
        }
#pragma unroll
        for (int q4 = 0; q4 < 4; ++q4) {
            int col = (W * 8 + p * 4 + q4) * 16 + lr;
            float pb = proj_b[col];
#pragma unroll
            for (int mt = 0; mt < 4; ++mt) {
#pragma unroll
                for (int r = 0; r < 4; ++r) {
                    int row = mt * 16 + lg * 4 + r;
                    if (row < 49) ow[row * 512 + col] = acc[q4][mt][r] + pb;
                }
            }
        }
    }
}

extern "C" void kernel_launch(void* const* d_in, const int* in_sizes, int n_in,
                              void* d_out, int out_size, void* d_ws, size_t ws_size,
                              hipStream_t stream) {
    const float* x          = (const float*)d_in[0];
    const float* qkv_w      = (const float*)d_in[1];
    const float* qkv_b      = (const float*)d_in[2];
    const float* proj_w     = (const float*)d_in[3];
    const float* proj_b     = (const float*)d_in[4];
    const float* bias_table = (const float*)d_in[5];

    unsigned short* wqkv_f  = (unsigned short*)d_ws;
    unsigned short* wproj_f = wqkv_f + 786432;                 // @1.5MB
    float*          bias_f  = (float*)(wproj_f + 262144);      // @2.0MB

    if (ws_size >= WS_NEW) {
        unsigned short* attnout = (unsigned short*)((char*)d_ws + 2359296);
        hipLaunchKernelGGL(prep2_kernel, dim3(768), dim3(256), 0, stream,
                           qkv_w, proj_w, bias_table, wqkv_f, wproj_f, bias_f);
        hipLaunchKernelGGL(attn_qkv_kernel, dim3(2048), dim3(256), 0, stream,
                           x, qkv_b, wqkv_f, bias_f, attnout);
        hipLaunchKernelGGL(proj_kernel, dim3(3136), dim3(256), 0, stream,
                           attnout, wproj_f, proj_b, (float*)d_out);
    } else if (ws_size >= 2359296u) {
        hipLaunchKernelGGL(prep_fb, dim3(768), dim3(256), 0, stream,
                           qkv_w, proj_w, bias_table, wqkv_f, wproj_f, bias_f);
        hipLaunchKernelGGL(winattn_fb, dim3(2048), dim3(256), 0, stream,
                           x, qkv_b, proj_b, wqkv_f, wproj_f, bias_f, (float*)d_out);
    }
}